// Round 1
// baseline (150.040 us; speedup 1.0000x reference)
//
#include <hip/hip_runtime.h>

// Embedding gather: out[t,f,l,:] = char2vec[x[t,f,l], :]
// x: [256*256*8] int ids, char2vec: [8000, 64] f32, out: [256*256*8*64] f32.
// One thread per float4 of output -> fully coalesced 16B/lane stores.
__global__ __launch_bounds__(256) void char2vec_gather(
    const int* __restrict__ x,
    const float4* __restrict__ cv,     // char2vec as float4 rows: [8000][16]
    float4* __restrict__ out,          // [n_rows][16]
    int n4)                            // total float4s = n_rows * 16
{
    int g = blockIdx.x * blockDim.x + threadIdx.x;
    const int stride = gridDim.x * blockDim.x;
    for (; g < n4; g += stride) {
        const int row = g >> 4;        // which id
        const int c   = g & 15;        // which float4 within the 64-float row
        const int id  = x[row];        // broadcast across 16 lanes, L1-hit
        out[g] = cv[id * 16 + c];      // table is 2 MiB -> L2-resident
    }
}

extern "C" void kernel_launch(void* const* d_in, const int* in_sizes, int n_in,
                              void* d_out, int out_size, void* d_ws, size_t ws_size,
                              hipStream_t stream) {
    const int*    x  = (const int*)d_in[0];      // [256*256*8] ids
    const float4* cv = (const float4*)d_in[1];   // [8000*64] f32 viewed as float4
    float4*       o  = (float4*)d_out;           // [out_size] f32 viewed as float4

    const int n4 = out_size / 4;                 // 8,388,608
    const int block = 256;
    int grid = (n4 + block - 1) / block;
    if (grid > 2048) grid = 2048;                // grid-stride beyond this

    char2vec_gather<<<grid, block, 0, stream>>>(x, cv, o, n4);
}